// Round 1
// baseline (317.030 us; speedup 1.0000x reference)
//
#include <hip/hip_runtime.h>
#include <hip/hip_bf16.h>
#include <math.h>

#define NROWS 64
#define SUBD 128   // d-elements per LDS tile

// ---------------------------------------------------------------------------
// Kernel 1: per-row cross-entropy (log_softmax + gather) and copy of logits
// into d_out[1:]. One block per row (64 rows, 1000 classes).
// ---------------------------------------------------------------------------
__global__ __launch_bounds__(256) void ce_kernel(
    const float* __restrict__ logits, const int* __restrict__ target,
    float* __restrict__ out_copy, float* __restrict__ ce_rows)
{
    const int row = blockIdx.x;
    const float* x = logits + row * 1000;
    const int t = threadIdx.x;
    __shared__ float red[256];

    float m = -INFINITY;
    for (int i = t; i < 1000; i += 256) {
        float v = x[i];
        out_copy[row * 1000 + i] = v;   // pass-through output
        m = fmaxf(m, v);
    }
    red[t] = m; __syncthreads();
    for (int s = 128; s > 0; s >>= 1) {
        if (t < s) red[t] = fmaxf(red[t], red[t + s]);
        __syncthreads();
    }
    m = red[0];
    __syncthreads();

    float ssum = 0.f;
    for (int i = t; i < 1000; i += 256) ssum += expf(x[i] - m);
    red[t] = ssum; __syncthreads();
    for (int s = 128; s > 0; s >>= 1) {
        if (t < s) red[t] += red[t + s];
        __syncthreads();
    }
    if (t == 0) {
        double lse = (double)m + log((double)red[0]);
        int tg = target[row];
        ce_rows[row] = (float)(-((double)x[tg] - lse));
    }
}

// ---------------------------------------------------------------------------
// Kernel 2: partial Gram matrices. Block = (feature, d-slice set).
// LDS tile stored d-major, transposed, with XOR swizzle on 8-row blocks so
// compute reads are ds_read_b128 with <=2-way bank conflicts.
// Each lane owns an 8x8 tile of K (rows 8a.., cols 8b..); the 4 waves of the
// block each handle a 32-d quarter of every 128-d subtile.
// ---------------------------------------------------------------------------
__global__ __launch_bounds__(256) void gram_kernel(
    const float* __restrict__ A, const float* __restrict__ B,
    float* __restrict__ partials, int nA, int nB)
{
    __shared__ float tile[SUBD * 64];   // 32 KiB

    const int blk = blockIdx.x;
    const float* X;
    int subs, strideBlocks, c;
    if (blk < 3 * nA) {
        int f = blk / nA; c = blk % nA;
        X = A + (size_t)f * NROWS * 65536;
        subs = 65536 / SUBD;            // 512
        strideBlocks = nA;
    } else {
        int b2 = blk - 3 * nA;
        int f = b2 / nB; c = b2 % nB;
        X = B + (size_t)f * NROWS * 32768;
        subs = 32768 / SUBD;            // 256
        strideBlocks = nB;
    }
    const int D = subs * SUBD;

    const int t = threadIdx.x;
    const int wave = t >> 6, lane = t & 63;
    const int ra = (lane >> 3) << 3;    // K row base
    const int cb = (lane & 7) << 3;     // K col base

    float acc[8][8];
#pragma unroll
    for (int i = 0; i < 8; ++i)
#pragma unroll
        for (int j = 0; j < 8; ++j) acc[i][j] = 0.f;

    for (int s = c; s < subs; s += strideBlocks) {
        const int d0 = s * SUBD;
        // ---- stage 128d x 64n into LDS (2048 float4 along d) ----
#pragma unroll
        for (int q = 0; q < 8; ++q) {
            int idx = t + q * 256;          // 0..2047
            int nn = idx >> 5;              // row 0..63
            int dq = idx & 31;              // float4 index in d
            float4 v = *(const float4*)(X + (size_t)nn * D + d0 + (dq << 2));
            float vv[4] = {v.x, v.y, v.z, v.w};
            int n8 = nn >> 3, nl = nn & 7;
#pragma unroll
            for (int k = 0; k < 4; ++k) {
                int d = (dq << 2) + k;
                int pos = (d << 6) + (((n8 ^ ((d >> 2) & 7)) << 3) | nl);
                tile[pos] = vv[k];
            }
        }
        __syncthreads();
        // ---- compute: this wave handles d in [wave*32, wave*32+32) ----
#pragma unroll 4
        for (int dd = 0; dd < 32; ++dd) {
            int d = (wave << 5) + dd;
            const float* rowp = &tile[d << 6];
            int x8 = (d >> 2) & 7;
            int ab = ((ra >> 3) ^ x8) << 3;
            int bb = ((cb >> 3) ^ x8) << 3;
            float ar[8], br[8];
#pragma unroll
            for (int i = 0; i < 8; ++i) ar[i] = rowp[ab + i];
#pragma unroll
            for (int j = 0; j < 8; ++j) br[j] = rowp[bb + j];
#pragma unroll
            for (int i = 0; i < 8; ++i)
#pragma unroll
                for (int j = 0; j < 8; ++j)
                    acc[i][j] = fmaf(ar[i], br[j], acc[i][j]);
        }
        __syncthreads();
    }

    // ---- cross-wave reduce via LDS (reuse tile as 4096-float K buffer) ----
    float* kred = tile;
    if (wave == 0) {
#pragma unroll
        for (int i = 0; i < 8; ++i)
#pragma unroll
            for (int j = 0; j < 8; ++j)
                kred[(ra + i) * 64 + cb + j] = acc[i][j];
    }
    __syncthreads();
    if (wave != 0) {
#pragma unroll
        for (int i = 0; i < 8; ++i)
#pragma unroll
            for (int j = 0; j < 8; ++j)
                atomicAdd(&kred[(ra + i) * 64 + cb + j], acc[i][j]);
    }
    __syncthreads();

    float* outp = partials + (size_t)blk * 4096;
    for (int e = t; e < 4096; e += 256) outp[e] = kred[e];
}

// ---------------------------------------------------------------------------
// Kernel 3: sum block partials -> 7 compact K matrices, zero the diagonal.
// ---------------------------------------------------------------------------
__global__ __launch_bounds__(256) void reduce_kernel(
    const float* __restrict__ partials, float* __restrict__ K, int nA, int nB)
{
    int gid = blockIdx.x * 256 + threadIdx.x;   // 0 .. 7*4096-1
    if (gid >= 7 * 4096) return;
    int f = gid >> 12, e = gid & 4095;
    int base, cnt;
    if (f < 3) { base = f * nA; cnt = nA; }
    else       { base = 3 * nA + (f - 3) * nB; cnt = nB; }
    double sum = 0.0;
    for (int j = 0; j < cnt; ++j)
        sum += (double)partials[(size_t)(base + j) * 4096 + e];
    int rr = e >> 6, cc = e & 63;
    K[gid] = (rr == cc) ? 0.f : (float)sum;     // fill_diagonal_(0)
}

// ---------------------------------------------------------------------------
// Kernel 4: HSIC/CKA in fp64 (tiny), combine with CE, write loss.
// ---------------------------------------------------------------------------
__global__ __launch_bounds__(256) void final_kernel(
    const float* __restrict__ K, const float* __restrict__ ce_rows,
    float* __restrict__ out_loss)
{
    __shared__ double red[256];
    __shared__ double trKL_s[25];
    __shared__ double rsum[7][64];
    __shared__ double ssum[7];
    const int t = threadIdx.x;

    // row sums r[f][n]
    for (int task = t; task < 7 * 64; task += 256) {
        int f = task >> 6, n = task & 63;
        const float* Kf = K + f * 4096 + n * 64;
        double s = 0.0;
        for (int m = 0; m < 64; ++m) s += (double)Kf[m];
        rsum[f][n] = s;
    }
    __syncthreads();
    if (t < 7) {
        double s = 0.0;
        for (int n = 0; n < 64; ++n) s += rsum[t][n];
        ssum[t] = s;
    }
    __syncthreads();

    // tr(Ki Kj) for in-group pairs: 9 (A) + 16 (B)
    for (int p = 0; p < 25; ++p) {
        int i, j;
        if (p < 9) { i = p / 3; j = p % 3; }
        else       { int q = p - 9; i = 3 + q / 4; j = 3 + q % 4; }
        const float* Ki = K + i * 4096;
        const float* Kj = K + j * 4096;
        double local = 0.0;
        for (int e = t; e < 4096; e += 256)
            local += (double)Ki[e] * (double)Kj[e];
        red[t] = local; __syncthreads();
        for (int s = 128; s > 0; s >>= 1) {
            if (t < s) red[t] += red[t + s];
            __syncthreads();
        }
        if (t == 0) trKL_s[p] = red[0];
        __syncthreads();
    }

    if (t == 0) {
        double ce = 0.0;
        for (int n = 0; n < 64; ++n) ce += (double)ce_rows[n];
        ce /= 64.0;

        const double N = 64.0;
        const double c1 = (N - 1.0) * (N - 2.0);
        const double c2 = N - 2.0;
        const double c3 = N * (N - 3.0);
        double cka_total = 0.0;

        {   // group A (features 0..2)
            double h[3][3];
            for (int p = 0; p < 9; ++p) {
                int i = p / 3, j = p % 3;
                double rr = 0.0;
                for (int n = 0; n < 64; ++n) rr += rsum[i][n] * rsum[j][n];
                h[i][j] = (trKL_s[p] + ssum[i] * ssum[j] / c1 - 2.0 * rr / c2) / c3;
            }
            for (int i = 0; i < 3; ++i)
                for (int j = 0; j < 3; ++j)
                    cka_total += h[i][j] / sqrt(h[i][i] * h[j][j]);
        }
        {   // group B (features 3..6)
            double h[4][4];
            for (int q = 0; q < 16; ++q) {
                int i = q / 4, j = q % 4;
                double rr = 0.0;
                for (int n = 0; n < 64; ++n) rr += rsum[3 + i][n] * rsum[3 + j][n];
                h[i][j] = (trKL_s[9 + q] + ssum[3 + i] * ssum[3 + j] / c1 - 2.0 * rr / c2) / c3;
            }
            for (int i = 0; i < 4; ++i)
                for (int j = 0; j < 4; ++j)
                    cka_total += h[i][j] / sqrt(h[i][i] * h[j][j]);
        }
        out_loss[0] = (float)(ce + 0.1 * cka_total);
    }
}

// ---------------------------------------------------------------------------
extern "C" void kernel_launch(void* const* d_in, const int* in_sizes, int n_in,
                              void* d_out, int out_size, void* d_ws, size_t ws_size,
                              hipStream_t stream)
{
    const float* output  = (const float*)d_in[0];
    const int*   target  = (const int*)d_in[1];
    const float* feats_a = (const float*)d_in[2];
    const float* feats_b = (const float*)d_in[3];
    float* out = (float*)d_out;

    char* ws = (char*)d_ws;
    float* K        = (float*)ws;                 // 7*4096 floats = 114688 B
    float* ce_rows  = (float*)(ws + 114688);      // 64 floats
    float* partials = (float*)(ws + 131072);      // nblocks * 4096 floats

    // choose block counts to fit workspace (all values divide 512 / 256)
    int nA = 128, nB = 64;
    for (;;) {
        size_t need = 131072 + (size_t)(3 * nA + 4 * nB) * 4096u * 4u;
        if (need <= ws_size || (nA == 1 && nB == 1)) break;
        nA = (nA > 1) ? (nA >> 1) : 1;
        nB = (nB > 1) ? (nB >> 1) : 1;
    }
    const int nblocks = 3 * nA + 4 * nB;

    hipLaunchKernelGGL(ce_kernel, dim3(64), dim3(256), 0, stream,
                       output, target, out + 1, ce_rows);
    hipLaunchKernelGGL(gram_kernel, dim3(nblocks), dim3(256), 0, stream,
                       feats_a, feats_b, partials, nA, nB);
    hipLaunchKernelGGL(reduce_kernel, dim3(112), dim3(256), 0, stream,
                       partials, K, nA, nB);
    hipLaunchKernelGGL(final_kernel, dim3(1), dim3(256), 0, stream,
                       K, ce_rows, out);
}

// Round 2
// 191.023 us; speedup vs baseline: 1.6596x; 1.6596x over previous
//
#include <hip/hip_runtime.h>
#include <hip/hip_bf16.h>
#include <math.h>

typedef __attribute__((ext_vector_type(8))) short short8;
typedef __attribute__((ext_vector_type(4))) float f32x4;

#define NROWS 64
#define KB    128          // fp32 k-elements staged per chunk
#define ROWP  136          // padded LDS row stride in bf16 elems (128 + 8)

// ---------------------------------------------------------------------------
// Kernel 1: per-row cross-entropy + logits pass-through copy.
// ---------------------------------------------------------------------------
__global__ __launch_bounds__(256) void ce_kernel(
    const float* __restrict__ logits, const int* __restrict__ target,
    float* __restrict__ out_copy, float* __restrict__ ce_rows)
{
    const int row = blockIdx.x;
    const float* x = logits + row * 1000;
    const int t = threadIdx.x;
    __shared__ float red[256];

    float m = -INFINITY;
    for (int i = t; i < 1000; i += 256) {
        float v = x[i];
        out_copy[row * 1000 + i] = v;
        m = fmaxf(m, v);
    }
    red[t] = m; __syncthreads();
    for (int s = 128; s > 0; s >>= 1) {
        if (t < s) red[t] = fmaxf(red[t], red[t + s]);
        __syncthreads();
    }
    m = red[0];
    __syncthreads();

    float ssum = 0.f;
    for (int i = t; i < 1000; i += 256) ssum += expf(x[i] - m);
    red[t] = ssum; __syncthreads();
    for (int s = 128; s > 0; s >>= 1) {
        if (t < s) red[t] += red[t + s];
        __syncthreads();
    }
    if (t == 0) {
        double lse = (double)m + log((double)red[0]);
        int tg = target[row];
        ce_rows[row] = (float)(-((double)x[tg] - lse));
    }
}

// ---------------------------------------------------------------------------
// round-to-nearest-even fp32 -> bf16 bits
// ---------------------------------------------------------------------------
__device__ __forceinline__ unsigned int bf16_rn(float x) {
    unsigned int u = __float_as_uint(x);
    return (u + 0x7FFFu + ((u >> 16) & 1u)) >> 16;
}

// ---------------------------------------------------------------------------
// Kernel 2: partial Gram via split-bf16 MFMA.
// Block = (feature, chunk-set). Per 128-d chunk: stage 64x128 fp32 as
// hi/lo bf16 rows in LDS (row stride 136 bf16 -> no pathological bank
// aliasing), each of 4 waves MFMAs one 32-k window into a full 64x64
// accumulator tile (16 mfma tiles x {hi.hi, hi.lo, lo.hi}).
// ---------------------------------------------------------------------------
__global__ __launch_bounds__(256) void gram_kernel(
    const float* __restrict__ A, const float* __restrict__ B,
    float* __restrict__ partials, int nA, int nB)
{
    __shared__ __align__(16) char smem[2 * NROWS * ROWP * 2];  // 34816 B
    ushort* Hi = (ushort*)smem;
    ushort* Lo = (ushort*)(smem + NROWS * ROWP * 2);
    float*  kbuf = (float*)smem;   // aliased after the chunk loop

    const int blk = blockIdx.x;
    const float* X;
    int subs, strideBlocks, c;
    if (blk < 3 * nA) {
        int f = blk / nA; c = blk % nA;
        X = A + (size_t)f * NROWS * 65536;
        subs = 65536 / KB;
        strideBlocks = nA;
    } else {
        int b2 = blk - 3 * nA;
        int f = b2 / nB; c = b2 % nB;
        X = B + (size_t)f * NROWS * 32768;
        subs = 32768 / KB;
        strideBlocks = nB;
    }
    const int D = subs * KB;

    const int t = threadIdx.x;
    const int wave = t >> 6, lane = t & 63;
    const int m = lane & 15, quad = lane >> 4;

    f32x4 acc[4][4];
#pragma unroll
    for (int i = 0; i < 4; ++i)
#pragma unroll
        for (int j = 0; j < 4; ++j) acc[i][j] = (f32x4)0.f;

    for (int s = c; s < subs; s += strideBlocks) {
        const int d0 = s * KB;
        // ---- stage: 2048 float4 loads, convert to hi/lo bf16, b64 writes ----
#pragma unroll
        for (int q = 0; q < 8; ++q) {
            int idx = t + q * 256;           // 0..2047
            int row = idx >> 5;              // 0..63
            int k4  = idx & 31;              // float4 index along k
            float4 v = *(const float4*)(X + (size_t)row * D + d0 + (k4 << 2));
            float vv[4] = {v.x, v.y, v.z, v.w};
            unsigned int hbits[4], lbits[4];
#pragma unroll
            for (int k = 0; k < 4; ++k) {
                unsigned int hb = bf16_rn(vv[k]);
                hbits[k] = hb;
                float hf = __uint_as_float(hb << 16);
                lbits[k] = bf16_rn(vv[k] - hf);
            }
            uint2 hp2, lp2;
            hp2.x = hbits[0] | (hbits[1] << 16);
            hp2.y = hbits[2] | (hbits[3] << 16);
            lp2.x = lbits[0] | (lbits[1] << 16);
            lp2.y = lbits[2] | (lbits[3] << 16);
            int base = row * ROWP + (k4 << 2);
            *(uint2*)(Hi + base) = hp2;
            *(uint2*)(Lo + base) = lp2;
        }
        __syncthreads();
        // ---- compute: this wave's 32-k window -> 48 MFMAs ----
        const int koff = (wave << 5) + (quad << 3);
        const ushort* hp = Hi + m * ROWP + koff;
        const ushort* lp = Lo + m * ROWP + koff;
        short8 hf[4], lf[4];
#pragma unroll
        for (int t4 = 0; t4 < 4; ++t4) {
            hf[t4] = *(const short8*)(hp + t4 * 16 * ROWP);
            lf[t4] = *(const short8*)(lp + t4 * 16 * ROWP);
        }
#pragma unroll
        for (int tm = 0; tm < 4; ++tm)
#pragma unroll
            for (int tn = 0; tn < 4; ++tn) {
                acc[tm][tn] = __builtin_amdgcn_mfma_f32_16x16x32_bf16(
                    hf[tm], hf[tn], acc[tm][tn], 0, 0, 0);
                acc[tm][tn] = __builtin_amdgcn_mfma_f32_16x16x32_bf16(
                    hf[tm], lf[tn], acc[tm][tn], 0, 0, 0);
                acc[tm][tn] = __builtin_amdgcn_mfma_f32_16x16x32_bf16(
                    lf[tm], hf[tn], acc[tm][tn], 0, 0, 0);
            }
        __syncthreads();
    }

    // ---- cross-wave reduce in LDS (C layout: row = quad*4+reg, col = m) ----
    if (wave == 0) {
#pragma unroll
        for (int tm = 0; tm < 4; ++tm)
#pragma unroll
            for (int tn = 0; tn < 4; ++tn)
#pragma unroll
                for (int r = 0; r < 4; ++r)
                    kbuf[(tm * 16 + quad * 4 + r) * 64 + tn * 16 + m] = acc[tm][tn][r];
    }
    __syncthreads();
    if (wave != 0) {
#pragma unroll
        for (int tm = 0; tm < 4; ++tm)
#pragma unroll
            for (int tn = 0; tn < 4; ++tn)
#pragma unroll
                for (int r = 0; r < 4; ++r)
                    atomicAdd(&kbuf[(tm * 16 + quad * 4 + r) * 64 + tn * 16 + m],
                              acc[tm][tn][r]);
    }
    __syncthreads();

    float4* outp = (float4*)(partials + (size_t)blk * 4096);
    const float4* kb4 = (const float4*)kbuf;
    for (int e = t; e < 1024; e += 256) outp[e] = kb4[e];
}

// ---------------------------------------------------------------------------
// Kernel 3: sum block partials -> 7 compact K matrices, zero the diagonal.
// ---------------------------------------------------------------------------
__global__ __launch_bounds__(256) void reduce_kernel(
    const float* __restrict__ partials, float* __restrict__ K, int nA, int nB)
{
    int gid = blockIdx.x * 256 + threadIdx.x;   // 0 .. 7*4096-1
    if (gid >= 7 * 4096) return;
    int f = gid >> 12, e = gid & 4095;
    int base, cnt;
    if (f < 3) { base = f * nA; cnt = nA; }
    else       { base = 3 * nA + (f - 3) * nB; cnt = nB; }
    double s0 = 0.0, s1 = 0.0, s2 = 0.0, s3 = 0.0;
    int j = 0;
    for (; j + 4 <= cnt; j += 4) {
        s0 += (double)partials[(size_t)(base + j + 0) * 4096 + e];
        s1 += (double)partials[(size_t)(base + j + 1) * 4096 + e];
        s2 += (double)partials[(size_t)(base + j + 2) * 4096 + e];
        s3 += (double)partials[(size_t)(base + j + 3) * 4096 + e];
    }
    for (; j < cnt; ++j) s0 += (double)partials[(size_t)(base + j) * 4096 + e];
    double sum = (s0 + s1) + (s2 + s3);
    int rr = e >> 6, cc = e & 63;
    K[gid] = (rr == cc) ? 0.f : (float)sum;     // fill_diagonal_(0)
}

// ---------------------------------------------------------------------------
// Kernel 4: one block per (i,j) pair -> unbiased HSIC(Ki,Kj) in fp64.
// 25 pairs: 9 in group A (features 0..2), 16 in group B (features 3..6).
// ---------------------------------------------------------------------------
__global__ __launch_bounds__(256) void hsic_kernel(
    const float* __restrict__ K, double* __restrict__ hsic_out)
{
    const int p = blockIdx.x;
    int i, j;
    if (p < 9) { i = p / 3; j = p % 3; }
    else       { int q = p - 9; i = 3 + q / 4; j = 3 + q % 4; }
    const float* Ki = K + i * 4096;
    const float* Kj = K + j * 4096;
    const int t = threadIdx.x;

    __shared__ double red[256];
    __shared__ double ri[64], rj[64];

    double local = 0.0;
    for (int e = t; e < 4096; e += 256)
        local += (double)Ki[e] * (double)Kj[e];
    red[t] = local; __syncthreads();
    for (int s = 128; s > 0; s >>= 1) {
        if (t < s) red[t] += red[t + s];
        __syncthreads();
    }

    if (t < 64) {
        double s = 0.0;
        for (int mcol = 0; mcol < 64; ++mcol) s += (double)Ki[t * 64 + mcol];
        ri[t] = s;
    } else if (t < 128) {
        int n = t - 64;
        double s = 0.0;
        for (int mcol = 0; mcol < 64; ++mcol) s += (double)Kj[n * 64 + mcol];
        rj[n] = s;
    }
    __syncthreads();

    if (t == 0) {
        double tr = red[0];
        double rr = 0.0, si = 0.0, sj = 0.0;
        for (int n = 0; n < 64; ++n) {
            rr += ri[n] * rj[n];
            si += ri[n];
            sj += rj[n];
        }
        const double N = 64.0;
        const double c1 = (N - 1.0) * (N - 2.0);
        const double c2 = N - 2.0;
        const double c3 = N * (N - 3.0);
        hsic_out[p] = (tr + si * sj / c1 - 2.0 * rr / c2) / c3;
    }
}

// ---------------------------------------------------------------------------
// Kernel 5: combine -> loss.
// ---------------------------------------------------------------------------
__global__ __launch_bounds__(64) void final_kernel(
    const double* __restrict__ hsic, const float* __restrict__ ce_rows,
    float* __restrict__ out_loss)
{
    if (threadIdx.x != 0) return;
    double ce = 0.0;
    for (int n = 0; n < 64; ++n) ce += (double)ce_rows[n];
    ce /= 64.0;

    double cka_total = 0.0;
    // group A: 3x3, hsic[i*3+j]
    for (int i = 0; i < 3; ++i)
        for (int j = 0; j < 3; ++j)
            cka_total += hsic[i * 3 + j] / sqrt(hsic[i * 3 + i] * hsic[j * 3 + j]);
    // group B: 4x4, hsic[9 + i*4 + j]
    for (int i = 0; i < 4; ++i)
        for (int j = 0; j < 4; ++j)
            cka_total += hsic[9 + i * 4 + j] / sqrt(hsic[9 + i * 4 + i] * hsic[9 + j * 4 + j]);

    out_loss[0] = (float)(ce + 0.1 * cka_total);
}

// ---------------------------------------------------------------------------
extern "C" void kernel_launch(void* const* d_in, const int* in_sizes, int n_in,
                              void* d_out, int out_size, void* d_ws, size_t ws_size,
                              hipStream_t stream)
{
    const float* output  = (const float*)d_in[0];
    const int*   target  = (const int*)d_in[1];
    const float* feats_a = (const float*)d_in[2];
    const float* feats_b = (const float*)d_in[3];
    float* out = (float*)d_out;

    char* ws = (char*)d_ws;
    float*  K        = (float*)ws;                 // 114688 B
    float*  ce_rows  = (float*)(ws + 114688);      // 256 B
    double* hsic     = (double*)(ws + 114944);     // 200 B
    float*  partials = (float*)(ws + 131072);

    int nA = 128, nB = 64;
    for (;;) {
        size_t need = 131072 + (size_t)(3 * nA + 4 * nB) * 4096u * 4u;
        if (need <= ws_size || (nA == 1 && nB == 1)) break;
        nA = (nA > 1) ? (nA >> 1) : 1;
        nB = (nB > 1) ? (nB >> 1) : 1;
    }
    const int nblocks = 3 * nA + 4 * nB;

    hipLaunchKernelGGL(ce_kernel, dim3(64), dim3(256), 0, stream,
                       output, target, out + 1, ce_rows);
    hipLaunchKernelGGL(gram_kernel, dim3(nblocks), dim3(256), 0, stream,
                       feats_a, feats_b, partials, nA, nB);
    hipLaunchKernelGGL(reduce_kernel, dim3(112), dim3(256), 0, stream,
                       partials, K, nA, nB);
    hipLaunchKernelGGL(hsic_kernel, dim3(25), dim3(256), 0, stream,
                       K, hsic);
    hipLaunchKernelGGL(final_kernel, dim3(1), dim3(64), 0, stream,
                       hsic, ce_rows, out);
}